// Round 15
// baseline (83.320 us; speedup 1.0000x reference)
//
#include <hip/hip_runtime.h>
#include <hip/hip_bf16.h>

// ---------------------------------------------------------------------------
// SAGEConv: out = relu(concat(feature, mean_{src->dst}(feature)) @ W + b)
// N=10000 nodes, E=160000 edges, D_IN=512, D_OUT=512, K=1024
// Round 15: gather quarter-column phases (2.5MB fits 4MB per-XCD L2) while
// KEEPING 8B/lane loads via half-wave edge pairing (lanes 0-31 edge j,
// lanes 32-63 edge j+1, shfl_xor(32) combine). Isolates L2-fit from load
// width (r11 vs r13 ambiguity). Everything else = round-14 best state.
// ---------------------------------------------------------------------------

#define N_NODES 10000
#define N_EDGES 160000
#define D_IN    512
#define D_OUT   512
#define K_DIM   1024

typedef float  f32x4  __attribute__((ext_vector_type(4)));
typedef __bf16 bf16x8 __attribute__((ext_vector_type(8)));
typedef unsigned short us8 __attribute__((ext_vector_type(8)));
typedef unsigned short us4 __attribute__((ext_vector_type(4)));

__device__ __forceinline__ unsigned short f2b(float f) {
    unsigned int u = __float_as_uint(f);
    unsigned int r = u + 0x7FFFu + ((u >> 16) & 1u);   // round-to-nearest-even
    return (unsigned short)(r >> 16);
}
__device__ __forceinline__ float b2f(unsigned short h) {
    return __uint_as_float(((unsigned int)h) << 16);
}
// global -> LDS direct 16B load. LDS dest is wave-uniform base + lane*16;
// global src is per-lane.
__device__ __forceinline__ void gl_lds16(const void* g, void* l) {
    auto gp = (const __attribute__((address_space(1))) unsigned int*)(uintptr_t)g;
    auto lp = (__attribute__((address_space(3))) unsigned int*)(uintptr_t)l;
    __builtin_amdgcn_global_load_lds(gp, lp, 16, 0, 0);
}

// ---------------------------------------------------------------------------
// Kernel 1 (runs FIRST): W [1024][512] fp32 -> WbT [512][1024] bf16,
// fused zeroing of cnt[10000]+cur[10000] (contiguous; 512 blocks x 40 ints).
// ---------------------------------------------------------------------------
__global__ __launch_bounds__(256) void wtrans_kernel(const float* __restrict__ W,
                                                     unsigned short* __restrict__ WbT,
                                                     int* __restrict__ cnt) {
    const int kt = blockIdx.x;   // 0..31
    const int nt = blockIdx.y;   // 0..15
    const int t  = threadIdx.x;

    const int bid = nt * 32 + kt;
    const int zi  = bid * 40 + t;
    if (t < 40 && zi < 2 * N_NODES) cnt[zi] = 0;   // cnt then cur

    __shared__ float tile[32][33];
    const int c  = t & 31;
    const int r0 = t >> 5;
#pragma unroll
    for (int p = 0; p < 4; ++p) {
        int r = r0 + p * 8;
        tile[r][c] = W[(size_t)(kt * 32 + r) * D_OUT + nt * 32 + c];
    }
    __syncthreads();
#pragma unroll
    for (int p = 0; p < 4; ++p) {
        int r = r0 + p * 8;
        WbT[(size_t)(nt * 32 + r) * K_DIM + kt * 32 + c] = f2b(tile[c][r]);
    }
}

// ---------------------------------------------------------------------------
// Kernel 2: feat fp32 -> Xb[:, :512] bf16, fused dst-histogram.
// ---------------------------------------------------------------------------
__global__ __launch_bounds__(256) void convert_hist_kernel(const float* __restrict__ feat,
                                                           const int* __restrict__ dst,
                                                           unsigned short* __restrict__ Xb,
                                                           int* __restrict__ cnt) {
    const int gid = blockIdx.x * 256 + threadIdx.x;
    const int row = gid >> 6;
    const int l   = gid & 63;
    const float4* s = (const float4*)(feat + (size_t)row * D_IN + l * 8);
    float4 v0 = s[0], v1 = s[1];
    us8 o;
    o[0] = f2b(v0.x); o[1] = f2b(v0.y); o[2] = f2b(v0.z); o[3] = f2b(v0.w);
    o[4] = f2b(v1.x); o[5] = f2b(v1.y); o[6] = f2b(v1.z); o[7] = f2b(v1.w);
    *(us8*)(Xb + (size_t)row * K_DIM + l * 8) = o;
    if (gid < N_EDGES) atomicAdd(&cnt[dst[gid]], 1);
}

// ---------------------------------------------------------------------------
// Kernel 3 (fused scan+bucket, 625 blocks): each block redundantly computes
// the exclusive scan of cnt[10000] into LDS (cnt is stable after kernel 2),
// block 0 publishes rowstart[10001] for the gather, then every block buckets
// its 256 edges: eidx[rs[d] + cur[d]++] = src.  cur zeroed by wtrans.
// ---------------------------------------------------------------------------
__global__ __launch_bounds__(256) void scanbucket_kernel(const int* __restrict__ src,
                                                         const int* __restrict__ dst,
                                                         const int* __restrict__ cnt,
                                                         int* __restrict__ rowstart,
                                                         int* __restrict__ cur,
                                                         int* __restrict__ eidx) {
    __shared__ int rs[N_NODES];    // 40 KB: exclusive prefix per node
    __shared__ int sums[256];
    const int t = threadIdx.x;
    const int base = t * 40;

    int4 v[10];
    int s = 0;
    if (base < N_NODES) {
        const int4* c4 = (const int4*)(cnt + base);
#pragma unroll
        for (int i = 0; i < 10; ++i) v[i] = c4[i];
#pragma unroll
        for (int i = 0; i < 10; ++i) s += v[i].x + v[i].y + v[i].z + v[i].w;
    }
    sums[t] = s;
    __syncthreads();
    for (int off = 1; off < 256; off <<= 1) {
        int x = (t >= off) ? sums[t - off] : 0;
        __syncthreads();
        sums[t] += x;
        __syncthreads();
    }
    int run = (t == 0) ? 0 : sums[t - 1];
    if (base < N_NODES) {
#pragma unroll
        for (int i = 0; i < 10; ++i) {
            rs[base + i * 4 + 0] = run; run += v[i].x;
            rs[base + i * 4 + 1] = run; run += v[i].y;
            rs[base + i * 4 + 2] = run; run += v[i].z;
            rs[base + i * 4 + 3] = run; run += v[i].w;
        }
    }
    __syncthreads();

    // block 0 publishes rowstart for the gather kernel
    if (blockIdx.x == 0) {
        for (int i = t; i < N_NODES; i += 256) rowstart[i] = rs[i];
        if (t == 0) rowstart[N_NODES] = N_EDGES;
    }

    // bucket fill
    const int e = blockIdx.x * 256 + t;
    const int d = dst[e];
    const int slot = rs[d] + atomicAdd(&cur[d], 1);
    eidx[slot] = src[e];
}

// ---------------------------------------------------------------------------
// Kernel 4: gather-mean (bf16 in, bf16 out), quarter-column phases with
// half-wave edge pairing. Blocks [q*2500,(q+1)*2500) -> cols [q*128,(q+1)*128).
// Lane l: half h = l>>5 processes edge j+h; 8B load per lane (4 shorts at
// col = q*128 + (l&31)*4); partial sums combined via shfl_xor(32).
// Per-phase source working set = 2.5MB -> fits 4MB per-XCD L2.
//   Xb[node][512:1024] = (1/max(deg,1)) * sum_j Xb[eidx[j]][0:512]
// ---------------------------------------------------------------------------
__global__ __launch_bounds__(256) void gather_kernel(unsigned short* Xb,
                                                     const int* __restrict__ eidx,
                                                     const int* __restrict__ rowstart) {
    const int wv    = threadIdx.x >> 6;
    const int l     = threadIdx.x & 63;
    const int h     = l >> 5;                       // half-wave 0/1
    const int phase = blockIdx.x / 2500;            // 0..3
    const int b     = blockIdx.x - phase * 2500;
    const int node  = b * 4 + wv;
    const int col   = phase * 128 + (l & 31) * 4;   // shorts
    const int beg   = rowstart[node];
    const int end   = rowstart[node + 1];
    float a0 = 0.f, a1 = 0.f, a2 = 0.f, a3 = 0.f;
    int j = beg;
    for (; j + 8 <= end; j += 8) {
        us4 v0 = *(const us4*)(Xb + (size_t)eidx[j + h]     * K_DIM + col);
        us4 v1 = *(const us4*)(Xb + (size_t)eidx[j + 2 + h] * K_DIM + col);
        us4 v2 = *(const us4*)(Xb + (size_t)eidx[j + 4 + h] * K_DIM + col);
        us4 v3 = *(const us4*)(Xb + (size_t)eidx[j + 6 + h] * K_DIM + col);
        a0 += (b2f(v0[0]) + b2f(v1[0])) + (b2f(v2[0]) + b2f(v3[0]));
        a1 += (b2f(v0[1]) + b2f(v1[1])) + (b2f(v2[1]) + b2f(v3[1]));
        a2 += (b2f(v0[2]) + b2f(v1[2])) + (b2f(v2[2]) + b2f(v3[2]));
        a3 += (b2f(v0[3]) + b2f(v1[3])) + (b2f(v2[3]) + b2f(v3[3]));
    }
    for (; j + 2 <= end; j += 2) {
        us4 v0 = *(const us4*)(Xb + (size_t)eidx[j + h] * K_DIM + col);
        a0 += b2f(v0[0]); a1 += b2f(v0[1]); a2 += b2f(v0[2]); a3 += b2f(v0[3]);
    }
    if (j < end && h == 0) {
        us4 v0 = *(const us4*)(Xb + (size_t)eidx[j] * K_DIM + col);
        a0 += b2f(v0[0]); a1 += b2f(v0[1]); a2 += b2f(v0[2]); a3 += b2f(v0[3]);
    }
    // combine the two half-wave partial sums
    a0 += __shfl_xor(a0, 32);
    a1 += __shfl_xor(a1, 32);
    a2 += __shfl_xor(a2, 32);
    a3 += __shfl_xor(a3, 32);
    if (h == 0) {
        float sc = 1.0f / fmaxf((float)(end - beg), 1.0f);
        us4 o;
        o[0] = f2b(a0 * sc); o[1] = f2b(a1 * sc);
        o[2] = f2b(a2 * sc); o[3] = f2b(a3 * sc);
        *(us4*)(Xb + (size_t)node * K_DIM + D_IN + col) = o;
    }
}

// ---------------------------------------------------------------------------
// Kernel 5: GEMM  out[10000][512] = relu( Xb[10000][1024] @ WbT^T + b )
// 128x64 tile, BK=64, 4 waves (2x2), 64x32 wave-tile, mfma 16x16x32 bf16.
// Double-buffered LDS via global_load_lds(16B); XOR-swizzle (row&7)<<4 on the
// global SOURCE address (linear LDS dest) and on the ds_read address.
// 640-slot grid (8 idle), XCD-grouped; LDS 48KB -> 3/CU.
// ---------------------------------------------------------------------------
__global__ __launch_bounds__(256, 3) void gemm_kernel(const unsigned short* __restrict__ Xb,
                                                      const unsigned short* __restrict__ WbT,
                                                      const float* __restrict__ bias,
                                                      float* __restrict__ out) {
    __shared__ __align__(16) unsigned short As[2][8192];   // [128 rows][64 k] bf16
    __shared__ __align__(16) unsigned short Bs[2][4096];   // [64 cols][64 k] bf16

    const int p    = blockIdx.x;      // 0..639
    const int xcd  = p & 7;
    const int rank = p >> 3;          // 0..79
    const int g    = xcd + 8 * (rank >> 3);   // row tile 0..79
    const int c    = rank & 7;                // col tile 0..7
    if (g >= 79) return;              // whole-block uniform exit (8 blocks)
    const int brow = g * 128;
    const int bcol = c * 64;

    const int tid = threadIdx.x;
    const int l   = tid & 63;
    const int w   = tid >> 6;
    const int wr  = w >> 1, wc = w & 1;

    const int sub  = l >> 3;
    const int scol = ((l & 7) * 16) ^ (sub * 16);   // inverse swizzle on source
    const char* pa[4];
    const char* pb[2];
#pragma unroll
    for (int q = 0; q < 4; ++q) {
        int ra = brow + q * 32 + w * 8 + sub;
        ra = ra < N_NODES ? ra : N_NODES - 1;
        pa[q] = (const char*)Xb + (size_t)ra * 2048 + scol;
    }
#pragma unroll
    for (int q = 0; q < 2; ++q)
        pb[q] = (const char*)WbT + (size_t)(bcol + q * 32 + w * 8 + sub) * 2048 + scol;

#define STAGE(buf, koff) do {                                          \
        gl_lds16(pa[0] + (koff), &As[buf][(0 * 32 + w * 8) * 64]);     \
        gl_lds16(pa[1] + (koff), &As[buf][(1 * 32 + w * 8) * 64]);     \
        gl_lds16(pa[2] + (koff), &As[buf][(2 * 32 + w * 8) * 64]);     \
        gl_lds16(pa[3] + (koff), &As[buf][(3 * 32 + w * 8) * 64]);     \
        gl_lds16(pb[0] + (koff), &Bs[buf][(0 * 32 + w * 8) * 64]);     \
        gl_lds16(pb[1] + (koff), &Bs[buf][(1 * 32 + w * 8) * 64]);     \
    } while (0)

    const int fr = l & 15;
    const int gq = l >> 4;
    const int sw = (fr & 7) * 16;
    const int h0 = ((gq * 16)      ^ sw) >> 1;   // kh=0, in shorts
    const int h1 = ((64 + gq * 16) ^ sw) >> 1;   // kh=1

    f32x4 acc[4][2] = {};

    STAGE(0, 0);
    __syncthreads();
#pragma unroll 2
    for (int t = 0; t < 16; ++t) {
        const int cur = t & 1;
        if (t < 15) STAGE(cur ^ 1, (t + 1) * 128);
        bf16x8 a[4][2], b[2][2];
#pragma unroll
        for (int m = 0; m < 4; ++m) {
            int r = (wr * 64 + m * 16 + fr) * 64;
            a[m][0] = *(const bf16x8*)&As[cur][r + h0];
            a[m][1] = *(const bf16x8*)&As[cur][r + h1];
        }
#pragma unroll
        for (int n = 0; n < 2; ++n) {
            int r = (wc * 32 + n * 16 + fr) * 64;
            b[n][0] = *(const bf16x8*)&Bs[cur][r + h0];
            b[n][1] = *(const bf16x8*)&Bs[cur][r + h1];
        }
#pragma unroll
        for (int kh = 0; kh < 2; ++kh)
#pragma unroll
            for (int m = 0; m < 4; ++m)
#pragma unroll
                for (int n = 0; n < 2; ++n)
                    acc[m][n] = __builtin_amdgcn_mfma_f32_16x16x32_bf16(a[m][kh], b[n][kh], acc[m][n], 0, 0, 0);
        __syncthreads();
    }
#undef STAGE

    // epilogue: bias + relu
#pragma unroll
    for (int n = 0; n < 2; ++n) {
        int col = bcol + wc * 32 + n * 16 + fr;
        float bv = bias[col];
#pragma unroll
        for (int m = 0; m < 4; ++m) {
            int row0 = brow + wr * 64 + m * 16 + gq * 4;
#pragma unroll
            for (int j = 0; j < 4; ++j) {
                int row = row0 + j;
                if (row < N_NODES)
                    out[(size_t)row * D_OUT + col] = fmaxf(acc[m][n][j] + bv, 0.0f);
            }
        }
    }
}

// ---------------------------------------------------------------------------
// Launch.  ws layout (bytes):
//   [0,          20480000)  Xb        bf16 [10000][1024] (left=feat, right=mean)
//   [20480000,   20520000)  cnt       int  [10000]   } zeroed together
//   [20520000,   20560000)  cur       int  [10000]   } by wtrans
//   [20560016,   20600032)  rowstart  int  [10001] (padded)
//   [20600032,   21240032)  eidx      int  [160000]
//   [21240032,   22288608)  WbT       bf16 [512][1024]
// ---------------------------------------------------------------------------
extern "C" void kernel_launch(void* const* d_in, const int* in_sizes, int n_in,
                              void* d_out, int out_size, void* d_ws, size_t ws_size,
                              hipStream_t stream) {
    const float* feat = (const float*)d_in[0];
    const int*   src  = (const int*)d_in[1];
    const int*   dst  = (const int*)d_in[2];
    const float* W    = (const float*)d_in[3];
    const float* bias = (const float*)d_in[4];
    float*       out  = (float*)d_out;

    char* ws = (char*)d_ws;
    unsigned short* Xb  = (unsigned short*)(ws);
    int*   cnt          = (int*)(ws + 20480000);
    int*   cur          = (int*)(ws + 20520000);
    int*   rowstart     = (int*)(ws + 20560016);
    int*   eidx         = (int*)(ws + 20600032);
    unsigned short* WbT = (unsigned short*)(ws + 21240032);

    wtrans_kernel<<<dim3(32, 16), 256, 0, stream>>>(W, WbT, cnt);   // zeroes cnt+cur
    convert_hist_kernel<<<2500, 256, 0, stream>>>(feat, dst, Xb, cnt);
    scanbucket_kernel<<<N_EDGES / 256, 256, 0, stream>>>(src, dst, cnt,
                                                         rowstart, cur, eidx);
    gather_kernel<<<10000, 256, 0, stream>>>(Xb, eidx, rowstart);
    gemm_kernel<<<640, 256, 0, stream>>>(Xb, WbT, bias, out);
}

// Round 16
// 81.182 us; speedup vs baseline: 1.0263x; 1.0263x over previous
//
#include <hip/hip_runtime.h>
#include <hip/hip_bf16.h>

// ---------------------------------------------------------------------------
// SAGEConv: out = relu(concat(feature, mean_{src->dst}(feature)) @ W + b)
// N=10000 nodes, E=160000 edges, D_IN=512, D_OUT=512, K=1024
// Round 16: revert to round-14 best state (81.3us). Gather locality ablation
// complete (r11/r13/r15): half-column phases + 8B/lane is the optimum; the
// gather is at its random-access floor. 5-dispatch chain is dependency-
// minimal (r7/r9: in-kernel cross-block sync costs 100s of us on 8 XCDs).
// ---------------------------------------------------------------------------

#define N_NODES 10000
#define N_EDGES 160000
#define D_IN    512
#define D_OUT   512
#define K_DIM   1024

typedef float  f32x4  __attribute__((ext_vector_type(4)));
typedef __bf16 bf16x8 __attribute__((ext_vector_type(8)));
typedef unsigned short us8 __attribute__((ext_vector_type(8)));
typedef unsigned short us4 __attribute__((ext_vector_type(4)));

__device__ __forceinline__ unsigned short f2b(float f) {
    unsigned int u = __float_as_uint(f);
    unsigned int r = u + 0x7FFFu + ((u >> 16) & 1u);   // round-to-nearest-even
    return (unsigned short)(r >> 16);
}
__device__ __forceinline__ float b2f(unsigned short h) {
    return __uint_as_float(((unsigned int)h) << 16);
}
// global -> LDS direct 16B load. LDS dest is wave-uniform base + lane*16;
// global src is per-lane.
__device__ __forceinline__ void gl_lds16(const void* g, void* l) {
    auto gp = (const __attribute__((address_space(1))) unsigned int*)(uintptr_t)g;
    auto lp = (__attribute__((address_space(3))) unsigned int*)(uintptr_t)l;
    __builtin_amdgcn_global_load_lds(gp, lp, 16, 0, 0);
}

// ---------------------------------------------------------------------------
// Kernel 1 (runs FIRST): W [1024][512] fp32 -> WbT [512][1024] bf16,
// fused zeroing of cnt[10000]+cur[10000] (contiguous; 512 blocks x 40 ints).
// ---------------------------------------------------------------------------
__global__ __launch_bounds__(256) void wtrans_kernel(const float* __restrict__ W,
                                                     unsigned short* __restrict__ WbT,
                                                     int* __restrict__ cnt) {
    const int kt = blockIdx.x;   // 0..31
    const int nt = blockIdx.y;   // 0..15
    const int t  = threadIdx.x;

    const int bid = nt * 32 + kt;
    const int zi  = bid * 40 + t;
    if (t < 40 && zi < 2 * N_NODES) cnt[zi] = 0;   // cnt then cur

    __shared__ float tile[32][33];
    const int c  = t & 31;
    const int r0 = t >> 5;
#pragma unroll
    for (int p = 0; p < 4; ++p) {
        int r = r0 + p * 8;
        tile[r][c] = W[(size_t)(kt * 32 + r) * D_OUT + nt * 32 + c];
    }
    __syncthreads();
#pragma unroll
    for (int p = 0; p < 4; ++p) {
        int r = r0 + p * 8;
        WbT[(size_t)(nt * 32 + r) * K_DIM + kt * 32 + c] = f2b(tile[c][r]);
    }
}

// ---------------------------------------------------------------------------
// Kernel 2: feat fp32 -> Xb[:, :512] bf16, fused dst-histogram.
// ---------------------------------------------------------------------------
__global__ __launch_bounds__(256) void convert_hist_kernel(const float* __restrict__ feat,
                                                           const int* __restrict__ dst,
                                                           unsigned short* __restrict__ Xb,
                                                           int* __restrict__ cnt) {
    const int gid = blockIdx.x * 256 + threadIdx.x;
    const int row = gid >> 6;
    const int l   = gid & 63;
    const float4* s = (const float4*)(feat + (size_t)row * D_IN + l * 8);
    float4 v0 = s[0], v1 = s[1];
    us8 o;
    o[0] = f2b(v0.x); o[1] = f2b(v0.y); o[2] = f2b(v0.z); o[3] = f2b(v0.w);
    o[4] = f2b(v1.x); o[5] = f2b(v1.y); o[6] = f2b(v1.z); o[7] = f2b(v1.w);
    *(us8*)(Xb + (size_t)row * K_DIM + l * 8) = o;
    if (gid < N_EDGES) atomicAdd(&cnt[dst[gid]], 1);
}

// ---------------------------------------------------------------------------
// Kernel 3 (fused scan+bucket, 625 blocks): each block redundantly computes
// the exclusive scan of cnt[10000] into LDS (cnt is stable after kernel 2),
// block 0 publishes rowstart[10001] for the gather, then every block buckets
// its 256 edges: eidx[rs[d] + cur[d]++] = src.  cur zeroed by wtrans.
// ---------------------------------------------------------------------------
__global__ __launch_bounds__(256) void scanbucket_kernel(const int* __restrict__ src,
                                                         const int* __restrict__ dst,
                                                         const int* __restrict__ cnt,
                                                         int* __restrict__ rowstart,
                                                         int* __restrict__ cur,
                                                         int* __restrict__ eidx) {
    __shared__ int rs[N_NODES];    // 40 KB: exclusive prefix per node
    __shared__ int sums[256];
    const int t = threadIdx.x;
    const int base = t * 40;

    int4 v[10];
    int s = 0;
    if (base < N_NODES) {
        const int4* c4 = (const int4*)(cnt + base);
#pragma unroll
        for (int i = 0; i < 10; ++i) v[i] = c4[i];
#pragma unroll
        for (int i = 0; i < 10; ++i) s += v[i].x + v[i].y + v[i].z + v[i].w;
    }
    sums[t] = s;
    __syncthreads();
    for (int off = 1; off < 256; off <<= 1) {
        int x = (t >= off) ? sums[t - off] : 0;
        __syncthreads();
        sums[t] += x;
        __syncthreads();
    }
    int run = (t == 0) ? 0 : sums[t - 1];
    if (base < N_NODES) {
#pragma unroll
        for (int i = 0; i < 10; ++i) {
            rs[base + i * 4 + 0] = run; run += v[i].x;
            rs[base + i * 4 + 1] = run; run += v[i].y;
            rs[base + i * 4 + 2] = run; run += v[i].z;
            rs[base + i * 4 + 3] = run; run += v[i].w;
        }
    }
    __syncthreads();

    // block 0 publishes rowstart for the gather kernel
    if (blockIdx.x == 0) {
        for (int i = t; i < N_NODES; i += 256) rowstart[i] = rs[i];
        if (t == 0) rowstart[N_NODES] = N_EDGES;
    }

    // bucket fill
    const int e = blockIdx.x * 256 + t;
    const int d = dst[e];
    const int slot = rs[d] + atomicAdd(&cur[d], 1);
    eidx[slot] = src[e];
}

// ---------------------------------------------------------------------------
// Kernel 4: gather-mean (bf16 in, bf16 out), phase-split column halves.
// Blocks [0,2500): cols [0,256); blocks [2500,5000): cols [256,512).
// One wave per node per phase; lane owns 8B; unroll-8.
//   Xb[node][512:1024] = (1/max(deg,1)) * sum_j Xb[eidx[j]][0:512]
// ---------------------------------------------------------------------------
__global__ __launch_bounds__(256) void gather_kernel(unsigned short* Xb,
                                                     const int* __restrict__ eidx,
                                                     const int* __restrict__ rowstart) {
    const int wv   = threadIdx.x >> 6;
    const int l    = threadIdx.x & 63;
    const int half = (blockIdx.x >= 2500) ? 1 : 0;
    const int b    = blockIdx.x - half * 2500;
    const int node = b * 4 + wv;
    const int col  = half * 256 + l * 4;            // shorts
    const int beg  = rowstart[node];
    const int end  = rowstart[node + 1];
    float a0 = 0.f, a1 = 0.f, a2 = 0.f, a3 = 0.f;
    int j = beg;
    for (; j + 8 <= end; j += 8) {
        us4 v0 = *(const us4*)(Xb + (size_t)eidx[j]     * K_DIM + col);
        us4 v1 = *(const us4*)(Xb + (size_t)eidx[j + 1] * K_DIM + col);
        us4 v2 = *(const us4*)(Xb + (size_t)eidx[j + 2] * K_DIM + col);
        us4 v3 = *(const us4*)(Xb + (size_t)eidx[j + 3] * K_DIM + col);
        us4 v4 = *(const us4*)(Xb + (size_t)eidx[j + 4] * K_DIM + col);
        us4 v5 = *(const us4*)(Xb + (size_t)eidx[j + 5] * K_DIM + col);
        us4 v6 = *(const us4*)(Xb + (size_t)eidx[j + 6] * K_DIM + col);
        us4 v7 = *(const us4*)(Xb + (size_t)eidx[j + 7] * K_DIM + col);
        a0 += ((b2f(v0[0]) + b2f(v1[0])) + (b2f(v2[0]) + b2f(v3[0])))
            + ((b2f(v4[0]) + b2f(v5[0])) + (b2f(v6[0]) + b2f(v7[0])));
        a1 += ((b2f(v0[1]) + b2f(v1[1])) + (b2f(v2[1]) + b2f(v3[1])))
            + ((b2f(v4[1]) + b2f(v5[1])) + (b2f(v6[1]) + b2f(v7[1])));
        a2 += ((b2f(v0[2]) + b2f(v1[2])) + (b2f(v2[2]) + b2f(v3[2])))
            + ((b2f(v4[2]) + b2f(v5[2])) + (b2f(v6[2]) + b2f(v7[2])));
        a3 += ((b2f(v0[3]) + b2f(v1[3])) + (b2f(v2[3]) + b2f(v3[3])))
            + ((b2f(v4[3]) + b2f(v5[3])) + (b2f(v6[3]) + b2f(v7[3])));
    }
    for (; j < end; ++j) {
        us4 v0 = *(const us4*)(Xb + (size_t)eidx[j] * K_DIM + col);
        a0 += b2f(v0[0]); a1 += b2f(v0[1]); a2 += b2f(v0[2]); a3 += b2f(v0[3]);
    }
    float sc = 1.0f / fmaxf((float)(end - beg), 1.0f);
    us4 o;
    o[0] = f2b(a0 * sc); o[1] = f2b(a1 * sc); o[2] = f2b(a2 * sc); o[3] = f2b(a3 * sc);
    *(us4*)(Xb + (size_t)node * K_DIM + D_IN + col) = o;
}

// ---------------------------------------------------------------------------
// Kernel 5: GEMM  out[10000][512] = relu( Xb[10000][1024] @ WbT^T + b )
// 128x64 tile, BK=64, 4 waves (2x2), 64x32 wave-tile, mfma 16x16x32 bf16.
// Double-buffered LDS via global_load_lds(16B); XOR-swizzle (row&7)<<4 on the
// global SOURCE address (linear LDS dest) and on the ds_read address.
// 640-slot grid (8 idle), XCD-grouped; LDS 48KB -> 3/CU.
// ---------------------------------------------------------------------------
__global__ __launch_bounds__(256, 3) void gemm_kernel(const unsigned short* __restrict__ Xb,
                                                      const unsigned short* __restrict__ WbT,
                                                      const float* __restrict__ bias,
                                                      float* __restrict__ out) {
    __shared__ __align__(16) unsigned short As[2][8192];   // [128 rows][64 k] bf16
    __shared__ __align__(16) unsigned short Bs[2][4096];   // [64 cols][64 k] bf16

    const int p    = blockIdx.x;      // 0..639
    const int xcd  = p & 7;
    const int rank = p >> 3;          // 0..79
    const int g    = xcd + 8 * (rank >> 3);   // row tile 0..79
    const int c    = rank & 7;                // col tile 0..7
    if (g >= 79) return;              // whole-block uniform exit (8 blocks)
    const int brow = g * 128;
    const int bcol = c * 64;

    const int tid = threadIdx.x;
    const int l   = tid & 63;
    const int w   = tid >> 6;
    const int wr  = w >> 1, wc = w & 1;

    const int sub  = l >> 3;
    const int scol = ((l & 7) * 16) ^ (sub * 16);   // inverse swizzle on source
    const char* pa[4];
    const char* pb[2];
#pragma unroll
    for (int q = 0; q < 4; ++q) {
        int ra = brow + q * 32 + w * 8 + sub;
        ra = ra < N_NODES ? ra : N_NODES - 1;
        pa[q] = (const char*)Xb + (size_t)ra * 2048 + scol;
    }
#pragma unroll
    for (int q = 0; q < 2; ++q)
        pb[q] = (const char*)WbT + (size_t)(bcol + q * 32 + w * 8 + sub) * 2048 + scol;

#define STAGE(buf, koff) do {                                          \
        gl_lds16(pa[0] + (koff), &As[buf][(0 * 32 + w * 8) * 64]);     \
        gl_lds16(pa[1] + (koff), &As[buf][(1 * 32 + w * 8) * 64]);     \
        gl_lds16(pa[2] + (koff), &As[buf][(2 * 32 + w * 8) * 64]);     \
        gl_lds16(pa[3] + (koff), &As[buf][(3 * 32 + w * 8) * 64]);     \
        gl_lds16(pb[0] + (koff), &Bs[buf][(0 * 32 + w * 8) * 64]);     \
        gl_lds16(pb[1] + (koff), &Bs[buf][(1 * 32 + w * 8) * 64]);     \
    } while (0)

    const int fr = l & 15;
    const int gq = l >> 4;
    const int sw = (fr & 7) * 16;
    const int h0 = ((gq * 16)      ^ sw) >> 1;   // kh=0, in shorts
    const int h1 = ((64 + gq * 16) ^ sw) >> 1;   // kh=1

    f32x4 acc[4][2] = {};

    STAGE(0, 0);
    __syncthreads();
#pragma unroll
    for (int t = 0; t < 16; ++t) {
        const int cur = t & 1;
        if (t < 15) STAGE(cur ^ 1, (t + 1) * 128);
        bf16x8 a[4][2], b[2][2];
#pragma unroll
        for (int m = 0; m < 4; ++m) {
            int r = (wr * 64 + m * 16 + fr) * 64;
            a[m][0] = *(const bf16x8*)&As[cur][r + h0];
            a[m][1] = *(const bf16x8*)&As[cur][r + h1];
        }
#pragma unroll
        for (int n = 0; n < 2; ++n) {
            int r = (wc * 32 + n * 16 + fr) * 64;
            b[n][0] = *(const bf16x8*)&Bs[cur][r + h0];
            b[n][1] = *(const bf16x8*)&Bs[cur][r + h1];
        }
#pragma unroll
        for (int kh = 0; kh < 2; ++kh)
#pragma unroll
            for (int m = 0; m < 4; ++m)
#pragma unroll
                for (int n = 0; n < 2; ++n)
                    acc[m][n] = __builtin_amdgcn_mfma_f32_16x16x32_bf16(a[m][kh], b[n][kh], acc[m][n], 0, 0, 0);
        __syncthreads();
    }
#undef STAGE

    // epilogue: bias + relu
#pragma unroll
    for (int n = 0; n < 2; ++n) {
        int col = bcol + wc * 32 + n * 16 + fr;
        float bv = bias[col];
#pragma unroll
        for (int m = 0; m < 4; ++m) {
            int row0 = brow + wr * 64 + m * 16 + gq * 4;
#pragma unroll
            for (int j = 0; j < 4; ++j) {
                int row = row0 + j;
                if (row < N_NODES)
                    out[(size_t)row * D_OUT + col] = fmaxf(acc[m][n][j] + bv, 0.0f);
            }
        }
    }
}

// ---------------------------------------------------------------------------
// Launch.  ws layout (bytes):
//   [0,          20480000)  Xb        bf16 [10000][1024] (left=feat, right=mean)
//   [20480000,   20520000)  cnt       int  [10000]   } zeroed together
//   [20520000,   20560000)  cur       int  [10000]   } by wtrans
//   [20560016,   20600032)  rowstart  int  [10001] (padded)
//   [20600032,   21240032)  eidx      int  [160000]
//   [21240032,   22288608)  WbT       bf16 [512][1024]
// ---------------------------------------------------------------------------
extern "C" void kernel_launch(void* const* d_in, const int* in_sizes, int n_in,
                              void* d_out, int out_size, void* d_ws, size_t ws_size,
                              hipStream_t stream) {
    const float* feat = (const float*)d_in[0];
    const int*   src  = (const int*)d_in[1];
    const int*   dst  = (const int*)d_in[2];
    const float* W    = (const float*)d_in[3];
    const float* bias = (const float*)d_in[4];
    float*       out  = (float*)d_out;

    char* ws = (char*)d_ws;
    unsigned short* Xb  = (unsigned short*)(ws);
    int*   cnt          = (int*)(ws + 20480000);
    int*   cur          = (int*)(ws + 20520000);
    int*   rowstart     = (int*)(ws + 20560016);
    int*   eidx         = (int*)(ws + 20600032);
    unsigned short* WbT = (unsigned short*)(ws + 21240032);

    wtrans_kernel<<<dim3(32, 16), 256, 0, stream>>>(W, WbT, cnt);   // zeroes cnt+cur
    convert_hist_kernel<<<2500, 256, 0, stream>>>(feat, dst, Xb, cnt);
    scanbucket_kernel<<<N_EDGES / 256, 256, 0, stream>>>(src, dst, cnt,
                                                         rowstart, cur, eidx);
    gather_kernel<<<5000, 256, 0, stream>>>(Xb, eidx, rowstart);
    gemm_kernel<<<640, 256, 0, stream>>>(Xb, WbT, bias, out);
}